// Round 1
// baseline (804.402 us; speedup 1.0000x reference)
//
#include <hip/hip_runtime.h>
#include <hip/hip_bf16.h>
#include <math.h>

typedef __bf16 bf16;
typedef __bf16 bf16x8 __attribute__((ext_vector_type(8)));
typedef float f32x4 __attribute__((ext_vector_type(4)));

#define EPS 1e-5f

__device__ __forceinline__ int swz16(int row, int byteoff) {
  return byteoff ^ ((row & 7) << 4);
}

__device__ __forceinline__ void st_lds_bf16x2(char* lds, int off, float a, float b) {
  union { bf16 h[2]; unsigned u; } pk;
  pk.h[0] = (bf16)a; pk.h[1] = (bf16)b;
  *(unsigned*)(lds + off) = pk.u;
}

// ---------------- prep: weights -> bf16 [N][K], rel_bias -> [6][64][64] ----------------
__global__ __launch_bounds__(256) void k_prep(
    const float* __restrict__ qkv_w, const float* __restrict__ proj_w,
    const float* __restrict__ mlp_w1, const float* __restrict__ mlp_w2,
    const float* __restrict__ rel_bias,
    bf16* __restrict__ w_qkv_t, bf16* __restrict__ w_proj_t,
    bf16* __restrict__ w_mlp1_t, bf16* __restrict__ w_mlp2_t,
    float* __restrict__ bias_tab) {
  int idx = blockIdx.x * 256 + threadIdx.x;
  if (idx < 110592) { int n = idx / 192, k = idx % 192; w_qkv_t[idx] = (bf16)qkv_w[k * 576 + n]; return; }
  idx -= 110592;
  if (idx < 36864) { int n = idx / 192, k = idx % 192; w_proj_t[idx] = (bf16)proj_w[k * 192 + n]; return; }
  idx -= 36864;
  if (idx < 147456) { int n = idx / 192, k = idx % 192; w_mlp1_t[idx] = (bf16)mlp_w1[k * 768 + n]; return; }
  idx -= 147456;
  if (idx < 147456) { int n = idx / 768, k = idx % 768; w_mlp2_t[idx] = (bf16)mlp_w2[k * 192 + n]; return; }
  idx -= 147456;
  {
    int h = idx >> 12, n = (idx >> 6) & 63, m = idx & 63;
    int i1 = n >> 3, j1 = n & 7, i2 = m >> 3, j2 = m & 7;
    int ridx = (i1 - i2 + 7) * 15 + (j1 - j2 + 7);
    bias_tab[idx] = rel_bias[ridx * 6 + h];
  }
}

// ---------------- K1: LN1 + window-partition(shifted) + QKV GEMM ----------------
// one block per window (2048), 256 threads = 4 waves. A tile 64x192 bf16 in LDS.
__global__ __launch_bounds__(256) void k1_ln_qkv(
    const float* __restrict__ x, const float* __restrict__ n1w, const float* __restrict__ n1b,
    const bf16* __restrict__ wqkv, const float* __restrict__ qkvb,
    bf16* __restrict__ qbuf, bf16* __restrict__ kbuf, bf16* __restrict__ vtbuf) {
  __shared__ alignas(16) char a_lds[64 * 384];
  const int win = blockIdx.x;
  const int bb = win >> 8, wi = (win >> 4) & 15, wj = win & 15;
  const int tid = threadIdx.x;
  {
    const int t = tid >> 2, q = tid & 3;
    const int i = t >> 3, j = t & 7;
    const int oh = (wi * 8 + i + 4) & 127, ow = (wj * 8 + j + 4) & 127;
    const float* xr = x + (((size_t)bb * 128 + oh) * 128 + ow) * 192 + q * 48;
    float v[48];
    float s = 0.f, ss = 0.f;
#pragma unroll
    for (int u = 0; u < 12; ++u) {
      float4 f = ((const float4*)xr)[u];
      v[4 * u] = f.x; v[4 * u + 1] = f.y; v[4 * u + 2] = f.z; v[4 * u + 3] = f.w;
      s += (f.x + f.y) + (f.z + f.w);
      ss += (f.x * f.x + f.y * f.y) + (f.z * f.z + f.w * f.w);
    }
    s += __shfl_xor(s, 1); s += __shfl_xor(s, 2);
    ss += __shfl_xor(ss, 1); ss += __shfl_xor(ss, 2);
    const float mean = s * (1.f / 192.f);
    const float rstd = rsqrtf(ss * (1.f / 192.f) - mean * mean + EPS);
#pragma unroll
    for (int u = 0; u < 24; ++u) {
      const int c = q * 48 + 2 * u;
      const float g0 = (v[2 * u] - mean) * rstd * n1w[c] + n1b[c];
      const float g1 = (v[2 * u + 1] - mean) * rstd * n1w[c + 1] + n1b[c + 1];
      st_lds_bf16x2(a_lds, swz16(t, t * 384 + c * 2), g0, g1);
    }
  }
  __syncthreads();
  const int wid = tid >> 6, lane = tid & 63, lr = lane & 15, lg = lane >> 4;
  const int colbase = wid * 144;
  f32x4 acc[4][9] = {};
#pragma unroll
  for (int ks = 0; ks < 6; ++ks) {
    bf16x8 af[4];
#pragma unroll
    for (int rf = 0; rf < 4; ++rf) {
      const int row = rf * 16 + lr;
      af[rf] = *(const bf16x8*)(a_lds + swz16(row, row * 384 + (ks * 32 + lg * 8) * 2));
    }
#pragma unroll
    for (int cf = 0; cf < 9; ++cf) {
      const int n = colbase + cf * 16 + lr;
      const bf16x8 bfr = *(const bf16x8*)(wqkv + n * 192 + ks * 32 + lg * 8);
#pragma unroll
      for (int rf = 0; rf < 4; ++rf)
        acc[rf][cf] = __builtin_amdgcn_mfma_f32_16x16x32_bf16(af[rf], bfr, acc[rf][cf], 0, 0, 0);
    }
  }
  const float scale = 0.1767766952966369f;  // 1/sqrt(32)
#pragma unroll
  for (int cf = 0; cf < 9; ++cf) {
    const int col0 = colbase + cf * 16;
    const int which = col0 / 192;
    const int rem = col0 - which * 192;
    const int head = rem >> 5;
    const int d = (rem & 31) + lr;
    const float bias = qkvb[col0 + lr];
    const size_t base = ((size_t)win * 6 + head) * 2048;
#pragma unroll
    for (int rf = 0; rf < 4; ++rf) {
#pragma unroll
      for (int jj = 0; jj < 4; ++jj) {
        const int tok = rf * 16 + lg * 4 + jj;
        const float val = acc[rf][cf][jj] + bias;
        if (which == 0)      qbuf[base + tok * 32 + d] = (bf16)(val * scale);
        else if (which == 1) kbuf[base + tok * 32 + d] = (bf16)val;
        else                 vtbuf[base + d * 64 + tok] = (bf16)val;
      }
    }
  }
}

// ---------------- K2: windowed attention, one wave per (window, head) ----------------
__global__ __launch_bounds__(64) void k2_attn(
    const bf16* __restrict__ qbuf, const bf16* __restrict__ kbuf,
    const bf16* __restrict__ vtbuf, const float* __restrict__ btab_all,
    bf16* __restrict__ obuf) {
  __shared__ alignas(16) char p_lds[64 * 128];
  const int head = blockIdx.x, win = blockIdx.y;
  const int wh = win * 6 + head;
  const int lane = threadIdx.x, lr = lane & 15, lg = lane >> 4;
  const bf16* qb = qbuf + (size_t)wh * 2048;
  const bf16* kb = kbuf + (size_t)wh * 2048;
  const bf16* vb = vtbuf + (size_t)wh * 2048;
  f32x4 sacc[4][4] = {};
  bf16x8 bk[4];
#pragma unroll
  for (int cf = 0; cf < 4; ++cf)
    bk[cf] = *(const bf16x8*)(kb + (cf * 16 + lr) * 32 + lg * 8);
#pragma unroll
  for (int rf = 0; rf < 4; ++rf) {
    const bf16x8 aq = *(const bf16x8*)(qb + (rf * 16 + lr) * 32 + lg * 8);
#pragma unroll
    for (int cf = 0; cf < 4; ++cf)
      sacc[rf][cf] = __builtin_amdgcn_mfma_f32_16x16x32_bf16(aq, bk[cf], sacc[rf][cf], 0, 0, 0);
  }
  const int wi = (win >> 4) & 15, wj = win & 15;
  const bool eh = (wi == 15), ew = (wj == 15);
  const float* btab = btab_all + head * 4096;
#pragma unroll
  for (int rf = 0; rf < 4; ++rf) {
#pragma unroll
    for (int jj = 0; jj < 4; ++jj) {
      const int n = rf * 16 + lg * 4 + jj;
      const int i1 = n >> 3, j1 = n & 7;
      float vals[4];
#pragma unroll
      for (int cf = 0; cf < 4; ++cf) {
        const int m = cf * 16 + lr;
        const int i2 = m >> 3, j2 = m & 7;
        float sv = sacc[rf][cf][jj] + btab[n * 64 + m];
        const bool msk = (eh && ((i1 >= 4) != (i2 >= 4))) || (ew && ((j1 >= 4) != (j2 >= 4)));
        if (msk) sv -= 100.f;
        vals[cf] = sv;
      }
      float mx = fmaxf(fmaxf(vals[0], vals[1]), fmaxf(vals[2], vals[3]));
      mx = fmaxf(mx, __shfl_xor(mx, 1));
      mx = fmaxf(mx, __shfl_xor(mx, 2));
      mx = fmaxf(mx, __shfl_xor(mx, 4));
      mx = fmaxf(mx, __shfl_xor(mx, 8));
      float sum = 0.f;
#pragma unroll
      for (int cf = 0; cf < 4; ++cf) { vals[cf] = __expf(vals[cf] - mx); sum += vals[cf]; }
      sum += __shfl_xor(sum, 1); sum += __shfl_xor(sum, 2);
      sum += __shfl_xor(sum, 4); sum += __shfl_xor(sum, 8);
      const float inv = 1.f / sum;
#pragma unroll
      for (int cf = 0; cf < 4; ++cf) {
        const int m = cf * 16 + lr;
        *(bf16*)(p_lds + swz16(n, n * 128 + m * 2)) = (bf16)(vals[cf] * inv);
      }
    }
  }
  __syncthreads();
  f32x4 oacc[4][2] = {};
#pragma unroll
  for (int ks = 0; ks < 2; ++ks) {
    bf16x8 pf[4];
#pragma unroll
    for (int rf = 0; rf < 4; ++rf) {
      const int row = rf * 16 + lr;
      pf[rf] = *(const bf16x8*)(p_lds + swz16(row, row * 128 + (ks * 32 + lg * 8) * 2));
    }
#pragma unroll
    for (int cf = 0; cf < 2; ++cf) {
      const bf16x8 vf = *(const bf16x8*)(vb + (cf * 16 + lr) * 64 + ks * 32 + lg * 8);
#pragma unroll
      for (int rf = 0; rf < 4; ++rf)
        oacc[rf][cf] = __builtin_amdgcn_mfma_f32_16x16x32_bf16(pf[rf], vf, oacc[rf][cf], 0, 0, 0);
    }
  }
  bf16* ob = obuf + (size_t)win * 64 * 192 + head * 32;
#pragma unroll
  for (int rf = 0; rf < 4; ++rf)
#pragma unroll
    for (int cf = 0; cf < 2; ++cf)
#pragma unroll
      for (int jj = 0; jj < 4; ++jj) {
        const int tok = rf * 16 + lg * 4 + jj;
        const int d = cf * 16 + lr;
        ob[(size_t)tok * 192 + d] = (bf16)oacc[rf][cf][jj];
      }
}

// ---------------- K3: proj GEMM + window-reverse + residual -> x2 (fp32) ----------------
__global__ __launch_bounds__(256) void k3_proj(
    const bf16* __restrict__ obuf, const bf16* __restrict__ wproj,
    const float* __restrict__ projb, const float* __restrict__ x,
    float* __restrict__ x2) {
  __shared__ alignas(16) char a_lds[128 * 384];
  const int blk = blockIdx.x;
  const int tid = threadIdx.x;
  const bf16* src = obuf + (size_t)blk * 128 * 192;
#pragma unroll
  for (int it = 0; it < 12; ++it) {
    const int chunk = it * 256 + tid;
    const int row = chunk / 24, c8 = chunk % 24;
    *(uint4*)(a_lds + swz16(row, row * 384 + c8 * 16)) = *(const uint4*)(src + chunk * 8);
  }
  __syncthreads();
  const int wid = tid >> 6, lane = tid & 63, lr = lane & 15, lg = lane >> 4;
  const int wr = wid >> 1, wc = wid & 1;
  f32x4 acc[4][6] = {};
#pragma unroll
  for (int ks = 0; ks < 6; ++ks) {
    bf16x8 af[4];
#pragma unroll
    for (int rf = 0; rf < 4; ++rf) {
      const int row = wr * 64 + rf * 16 + lr;
      af[rf] = *(const bf16x8*)(a_lds + swz16(row, row * 384 + (ks * 32 + lg * 8) * 2));
    }
#pragma unroll
    for (int cf = 0; cf < 6; ++cf) {
      const int n = wc * 96 + cf * 16 + lr;
      const bf16x8 bfr = *(const bf16x8*)(wproj + n * 192 + ks * 32 + lg * 8);
#pragma unroll
      for (int rf = 0; rf < 4; ++rf)
        acc[rf][cf] = __builtin_amdgcn_mfma_f32_16x16x32_bf16(af[rf], bfr, acc[rf][cf], 0, 0, 0);
    }
  }
#pragma unroll
  for (int rf = 0; rf < 4; ++rf) {
#pragma unroll
    for (int jj = 0; jj < 4; ++jj) {
      const int grow = blk * 128 + wr * 64 + rf * 16 + lg * 4 + jj;
      const int win = grow >> 6, t = grow & 63;
      const int bb = win >> 8, wi = (win >> 4) & 15, wj = win & 15;
      const int oh = (wi * 8 + (t >> 3) + 4) & 127, ow = (wj * 8 + (t & 7) + 4) & 127;
      const size_t orow = (((size_t)bb * 128 + oh) * 128 + ow) * 192;
#pragma unroll
      for (int cf = 0; cf < 6; ++cf) {
        const int col = wc * 96 + cf * 16 + lr;
        x2[orow + col] = x[orow + col] + acc[rf][cf][jj] + projb[col];
      }
    }
  }
}

// ---------------- K4: LN2 + MLP(768, gelu) + residual -> out ----------------
// 512 threads = 8 waves, 64 rows/block. h1 tile in LDS (96KB).
__global__ __launch_bounds__(512) void k4_mlp(
    const float* __restrict__ x2, const float* __restrict__ n2w, const float* __restrict__ n2b,
    const bf16* __restrict__ w1t, const float* __restrict__ b1,
    const bf16* __restrict__ w2t, const float* __restrict__ b2,
    float* __restrict__ out) {
  __shared__ alignas(16) char a_lds[64 * 384];
  __shared__ alignas(16) char h_lds[64 * 1536];
  const int blk = blockIdx.x;
  const int tid = threadIdx.x;
  {
    const int t = tid >> 3, q = tid & 7;
    const float* xr = x2 + ((size_t)blk * 64 + t) * 192 + q * 24;
    float v[24];
    float s = 0.f, ss = 0.f;
#pragma unroll
    for (int u = 0; u < 6; ++u) {
      float4 f = ((const float4*)xr)[u];
      v[4 * u] = f.x; v[4 * u + 1] = f.y; v[4 * u + 2] = f.z; v[4 * u + 3] = f.w;
      s += (f.x + f.y) + (f.z + f.w);
      ss += (f.x * f.x + f.y * f.y) + (f.z * f.z + f.w * f.w);
    }
    s += __shfl_xor(s, 1); s += __shfl_xor(s, 2); s += __shfl_xor(s, 4);
    ss += __shfl_xor(ss, 1); ss += __shfl_xor(ss, 2); ss += __shfl_xor(ss, 4);
    const float mean = s * (1.f / 192.f);
    const float rstd = rsqrtf(ss * (1.f / 192.f) - mean * mean + EPS);
#pragma unroll
    for (int u = 0; u < 12; ++u) {
      const int c = q * 24 + 2 * u;
      const float g0 = (v[2 * u] - mean) * rstd * n2w[c] + n2b[c];
      const float g1 = (v[2 * u + 1] - mean) * rstd * n2w[c + 1] + n2b[c + 1];
      st_lds_bf16x2(a_lds, swz16(t, t * 384 + c * 2), g0, g1);
    }
  }
  __syncthreads();
  const int wid = tid >> 6, lane = tid & 63, lr = lane & 15, lg = lane >> 4;
  // GEMM1: 64x768, wave w covers cols w*96..w*96+95
  {
    f32x4 acc[4][6] = {};
#pragma unroll
    for (int ks = 0; ks < 6; ++ks) {
      bf16x8 af[4];
#pragma unroll
      for (int rf = 0; rf < 4; ++rf) {
        const int row = rf * 16 + lr;
        af[rf] = *(const bf16x8*)(a_lds + swz16(row, row * 384 + (ks * 32 + lg * 8) * 2));
      }
#pragma unroll
      for (int cf = 0; cf < 6; ++cf) {
        const int n = wid * 96 + cf * 16 + lr;
        const bf16x8 bfr = *(const bf16x8*)(w1t + n * 192 + ks * 32 + lg * 8);
#pragma unroll
        for (int rf = 0; rf < 4; ++rf)
          acc[rf][cf] = __builtin_amdgcn_mfma_f32_16x16x32_bf16(af[rf], bfr, acc[rf][cf], 0, 0, 0);
      }
    }
#pragma unroll
    for (int cf = 0; cf < 6; ++cf) {
      const int col = wid * 96 + cf * 16 + lr;
      const float bb1 = b1[col];
#pragma unroll
      for (int rf = 0; rf < 4; ++rf)
#pragma unroll
        for (int jj = 0; jj < 4; ++jj) {
          const int hrow = rf * 16 + lg * 4 + jj;
          const float vv = acc[rf][cf][jj] + bb1;
          const float g = 0.5f * vv * (1.f + erff(vv * 0.70710678f));
          *(bf16*)(h_lds + swz16(hrow, hrow * 1536 + col * 2)) = (bf16)g;
        }
    }
  }
  __syncthreads();
  // GEMM2: 64x192, K=768. wave w: rows (w>>1)*16, cols (w&1)*96
  {
    const int rfx = wid >> 1, wc = wid & 1;
    f32x4 acc2[6] = {};
#pragma unroll
    for (int ks = 0; ks < 24; ++ks) {
      const int row = rfx * 16 + lr;
      const bf16x8 af = *(const bf16x8*)(h_lds + swz16(row, row * 1536 + (ks * 32 + lg * 8) * 2));
#pragma unroll
      for (int cf = 0; cf < 6; ++cf) {
        const int n = wc * 96 + cf * 16 + lr;
        const bf16x8 bfr = *(const bf16x8*)(w2t + n * 768 + ks * 32 + lg * 8);
        acc2[cf] = __builtin_amdgcn_mfma_f32_16x16x32_bf16(af, bfr, acc2[cf], 0, 0, 0);
      }
    }
#pragma unroll
    for (int jj = 0; jj < 4; ++jj) {
      const size_t grow = (size_t)blk * 64 + rfx * 16 + lg * 4 + jj;
#pragma unroll
      for (int cf = 0; cf < 6; ++cf) {
        const int col = wc * 96 + cf * 16 + lr;
        out[grow * 192 + col] = x2[grow * 192 + col] + acc2[cf][jj] + b2[col];
      }
    }
  }
}

extern "C" void kernel_launch(void* const* d_in, const int* in_sizes, int n_in,
                              void* d_out, int out_size, void* d_ws, size_t ws_size,
                              hipStream_t stream) {
  (void)in_sizes; (void)n_in; (void)out_size; (void)ws_size;
  const float* x     = (const float*)d_in[0];
  const float* n1w   = (const float*)d_in[1];
  const float* n1b   = (const float*)d_in[2];
  const float* qkv_w = (const float*)d_in[3];
  const float* qkv_b = (const float*)d_in[4];
  const float* rel_b = (const float*)d_in[5];
  const float* proj_w= (const float*)d_in[6];
  const float* proj_b= (const float*)d_in[7];
  const float* n2w   = (const float*)d_in[8];
  const float* n2b   = (const float*)d_in[9];
  const float* w1    = (const float*)d_in[10];
  const float* b1    = (const float*)d_in[11];
  const float* w2    = (const float*)d_in[12];
  const float* b2    = (const float*)d_in[13];
  float* out = (float*)d_out;

  char* ws = (char*)d_ws;
  size_t off = 0;
  auto alloc = [&](size_t bytes) { char* p = ws + off; off += (bytes + 255) & ~(size_t)255; return p; };
  bf16* w_qkv_t  = (bf16*)alloc(576 * 192 * 2);
  bf16* w_proj_t = (bf16*)alloc(192 * 192 * 2);
  bf16* w_mlp1_t = (bf16*)alloc(768 * 192 * 2);
  bf16* w_mlp2_t = (bf16*)alloc(192 * 768 * 2);
  float* bias_tab = (float*)alloc(6 * 64 * 64 * 4);
  bf16* qbuf  = (bf16*)alloc((size_t)2048 * 6 * 64 * 32 * 2);
  bf16* kbuf  = (bf16*)alloc((size_t)2048 * 6 * 64 * 32 * 2);
  bf16* vtbuf = (bf16*)alloc((size_t)2048 * 6 * 64 * 32 * 2);
  bf16* obuf  = (bf16*)alloc((size_t)131072 * 192 * 2);
  float* x2   = (float*)alloc((size_t)131072 * 192 * 4);

  k_prep<<<1824, 256, 0, stream>>>(qkv_w, proj_w, w1, w2, rel_b,
                                   w_qkv_t, w_proj_t, w_mlp1_t, w_mlp2_t, bias_tab);
  k1_ln_qkv<<<2048, 256, 0, stream>>>(x, n1w, n1b, w_qkv_t, qkv_b, qbuf, kbuf, vtbuf);
  k2_attn<<<dim3(6, 2048), 64, 0, stream>>>(qbuf, kbuf, vtbuf, bias_tab, obuf);
  k3_proj<<<1024, 256, 0, stream>>>(obuf, w_proj_t, proj_b, x, x2);
  k4_mlp<<<2048, 512, 0, stream>>>(x2, n2w, n2b, w_mlp1_t, b1, w_mlp2_t, b2, out);
}

// Round 2
// 767.775 us; speedup vs baseline: 1.0477x; 1.0477x over previous
//
#include <hip/hip_runtime.h>
#include <hip/hip_bf16.h>
#include <math.h>

typedef __bf16 bf16;
typedef __bf16 bf16x8 __attribute__((ext_vector_type(8)));
typedef float f32x4 __attribute__((ext_vector_type(4)));

#define EPS 1e-5f

__device__ __forceinline__ int swz16(int row, int byteoff) {
  return byteoff ^ ((row & 7) << 4);
}

__device__ __forceinline__ void st_lds_bf16x2(char* lds, int off, float a, float b) {
  union { bf16 h[2]; unsigned u; } pk;
  pk.h[0] = (bf16)a; pk.h[1] = (bf16)b;
  *(unsigned*)(lds + off) = pk.u;
}

// ---------------- prep: weights -> bf16 [N][K], rel_bias -> [6][64][64] ----------------
__global__ __launch_bounds__(256) void k_prep(
    const float* __restrict__ qkv_w, const float* __restrict__ proj_w,
    const float* __restrict__ mlp_w1, const float* __restrict__ mlp_w2,
    const float* __restrict__ rel_bias,
    bf16* __restrict__ w_qkv_t, bf16* __restrict__ w_proj_t,
    bf16* __restrict__ w_mlp1_t, bf16* __restrict__ w_mlp2_t,
    float* __restrict__ bias_tab) {
  int idx = blockIdx.x * 256 + threadIdx.x;
  if (idx < 110592) { int n = idx / 192, k = idx % 192; w_qkv_t[idx] = (bf16)qkv_w[k * 576 + n]; return; }
  idx -= 110592;
  if (idx < 36864) { int n = idx / 192, k = idx % 192; w_proj_t[idx] = (bf16)proj_w[k * 192 + n]; return; }
  idx -= 36864;
  if (idx < 147456) { int n = idx / 192, k = idx % 192; w_mlp1_t[idx] = (bf16)mlp_w1[k * 768 + n]; return; }
  idx -= 147456;
  if (idx < 147456) { int n = idx / 768, k = idx % 768; w_mlp2_t[idx] = (bf16)mlp_w2[k * 192 + n]; return; }
  idx -= 147456;
  {
    int h = idx >> 12, n = (idx >> 6) & 63, m = idx & 63;
    int i1 = n >> 3, j1 = n & 7, i2 = m >> 3, j2 = m & 7;
    int ridx = (i1 - i2 + 7) * 15 + (j1 - j2 + 7);
    bias_tab[idx] = rel_bias[ridx * 6 + h];
  }
}

// ---------------- K1: LN1 + window-partition(shifted) + QKV GEMM ----------------
__global__ __launch_bounds__(256) void k1_ln_qkv(
    const float* __restrict__ x, const float* __restrict__ n1w, const float* __restrict__ n1b,
    const bf16* __restrict__ wqkv, const float* __restrict__ qkvb,
    bf16* __restrict__ qbuf, bf16* __restrict__ kbuf, bf16* __restrict__ vtbuf) {
  __shared__ alignas(16) char a_lds[64 * 384];
  const int win = blockIdx.x;
  const int bb = win >> 8, wi = (win >> 4) & 15, wj = win & 15;
  const int tid = threadIdx.x;
  {
    const int t = tid >> 2, q = tid & 3;
    const int i = t >> 3, j = t & 7;
    const int oh = (wi * 8 + i + 4) & 127, ow = (wj * 8 + j + 4) & 127;
    const float* xr = x + (((size_t)bb * 128 + oh) * 128 + ow) * 192 + q * 48;
    float v[48];
    float s = 0.f, ss = 0.f;
#pragma unroll
    for (int u = 0; u < 12; ++u) {
      float4 f = ((const float4*)xr)[u];
      v[4 * u] = f.x; v[4 * u + 1] = f.y; v[4 * u + 2] = f.z; v[4 * u + 3] = f.w;
      s += (f.x + f.y) + (f.z + f.w);
      ss += (f.x * f.x + f.y * f.y) + (f.z * f.z + f.w * f.w);
    }
    s += __shfl_xor(s, 1); s += __shfl_xor(s, 2);
    ss += __shfl_xor(ss, 1); ss += __shfl_xor(ss, 2);
    const float mean = s * (1.f / 192.f);
    const float rstd = rsqrtf(ss * (1.f / 192.f) - mean * mean + EPS);
#pragma unroll
    for (int u = 0; u < 24; ++u) {
      const int c = q * 48 + 2 * u;
      const float g0 = (v[2 * u] - mean) * rstd * n1w[c] + n1b[c];
      const float g1 = (v[2 * u + 1] - mean) * rstd * n1w[c + 1] + n1b[c + 1];
      st_lds_bf16x2(a_lds, swz16(t, t * 384 + c * 2), g0, g1);
    }
  }
  __syncthreads();
  const int wid = tid >> 6, lane = tid & 63, lr = lane & 15, lg = lane >> 4;
  const int colbase = wid * 144;
  f32x4 acc[4][9] = {};
#pragma unroll
  for (int ks = 0; ks < 6; ++ks) {
    bf16x8 af[4];
#pragma unroll
    for (int rf = 0; rf < 4; ++rf) {
      const int row = rf * 16 + lr;
      af[rf] = *(const bf16x8*)(a_lds + swz16(row, row * 384 + (ks * 32 + lg * 8) * 2));
    }
#pragma unroll
    for (int cf = 0; cf < 9; ++cf) {
      const int n = colbase + cf * 16 + lr;
      const bf16x8 bfr = *(const bf16x8*)(wqkv + n * 192 + ks * 32 + lg * 8);
#pragma unroll
      for (int rf = 0; rf < 4; ++rf)
        acc[rf][cf] = __builtin_amdgcn_mfma_f32_16x16x32_bf16(af[rf], bfr, acc[rf][cf], 0, 0, 0);
    }
  }
  const float scale = 0.1767766952966369f;  // 1/sqrt(32)
#pragma unroll
  for (int cf = 0; cf < 9; ++cf) {
    const int col0 = colbase + cf * 16;
    const int which = col0 / 192;
    const int rem = col0 - which * 192;
    const int head = rem >> 5;
    const int d = (rem & 31) + lr;
    const float bias = qkvb[col0 + lr];
    const size_t base = ((size_t)win * 6 + head) * 2048;
#pragma unroll
    for (int rf = 0; rf < 4; ++rf) {
#pragma unroll
      for (int jj = 0; jj < 4; ++jj) {
        const int tok = rf * 16 + lg * 4 + jj;
        const float val = acc[rf][cf][jj] + bias;
        if (which == 0)      qbuf[base + tok * 32 + d] = (bf16)(val * scale);
        else if (which == 1) kbuf[base + tok * 32 + d] = (bf16)val;
        else                 vtbuf[base + d * 64 + tok] = (bf16)val;
      }
    }
  }
}

// ---------------- K2: windowed attention, one wave per (window, head) ----------------
__global__ __launch_bounds__(64) void k2_attn(
    const bf16* __restrict__ qbuf, const bf16* __restrict__ kbuf,
    const bf16* __restrict__ vtbuf, const float* __restrict__ btab_all,
    bf16* __restrict__ obuf) {
  __shared__ alignas(16) char p_lds[64 * 128];
  const int head = blockIdx.x, win = blockIdx.y;
  const int wh = win * 6 + head;
  const int lane = threadIdx.x, lr = lane & 15, lg = lane >> 4;
  const bf16* qb = qbuf + (size_t)wh * 2048;
  const bf16* kb = kbuf + (size_t)wh * 2048;
  const bf16* vb = vtbuf + (size_t)wh * 2048;
  f32x4 sacc[4][4] = {};
  bf16x8 bk[4];
#pragma unroll
  for (int cf = 0; cf < 4; ++cf)
    bk[cf] = *(const bf16x8*)(kb + (cf * 16 + lr) * 32 + lg * 8);
#pragma unroll
  for (int rf = 0; rf < 4; ++rf) {
    const bf16x8 aq = *(const bf16x8*)(qb + (rf * 16 + lr) * 32 + lg * 8);
#pragma unroll
    for (int cf = 0; cf < 4; ++cf)
      sacc[rf][cf] = __builtin_amdgcn_mfma_f32_16x16x32_bf16(aq, bk[cf], sacc[rf][cf], 0, 0, 0);
  }
  const int wi = (win >> 4) & 15, wj = win & 15;
  const bool eh = (wi == 15), ew = (wj == 15);
  const float* btab = btab_all + head * 4096;
#pragma unroll
  for (int rf = 0; rf < 4; ++rf) {
#pragma unroll
    for (int jj = 0; jj < 4; ++jj) {
      const int n = rf * 16 + lg * 4 + jj;
      const int i1 = n >> 3, j1 = n & 7;
      float vals[4];
#pragma unroll
      for (int cf = 0; cf < 4; ++cf) {
        const int m = cf * 16 + lr;
        const int i2 = m >> 3, j2 = m & 7;
        float sv = sacc[rf][cf][jj] + btab[n * 64 + m];
        const bool msk = (eh && ((i1 >= 4) != (i2 >= 4))) || (ew && ((j1 >= 4) != (j2 >= 4)));
        if (msk) sv -= 100.f;
        vals[cf] = sv;
      }
      float mx = fmaxf(fmaxf(vals[0], vals[1]), fmaxf(vals[2], vals[3]));
      mx = fmaxf(mx, __shfl_xor(mx, 1));
      mx = fmaxf(mx, __shfl_xor(mx, 2));
      mx = fmaxf(mx, __shfl_xor(mx, 4));
      mx = fmaxf(mx, __shfl_xor(mx, 8));
      float sum = 0.f;
#pragma unroll
      for (int cf = 0; cf < 4; ++cf) { vals[cf] = __expf(vals[cf] - mx); sum += vals[cf]; }
      sum += __shfl_xor(sum, 1); sum += __shfl_xor(sum, 2);
      sum += __shfl_xor(sum, 4); sum += __shfl_xor(sum, 8);
      const float inv = 1.f / sum;
#pragma unroll
      for (int cf = 0; cf < 4; ++cf) {
        const int m = cf * 16 + lr;
        *(bf16*)(p_lds + swz16(n, n * 128 + m * 2)) = (bf16)(vals[cf] * inv);
      }
    }
  }
  __syncthreads();
  f32x4 oacc[4][2] = {};
#pragma unroll
  for (int ks = 0; ks < 2; ++ks) {
    bf16x8 pf[4];
#pragma unroll
    for (int rf = 0; rf < 4; ++rf) {
      const int row = rf * 16 + lr;
      pf[rf] = *(const bf16x8*)(p_lds + swz16(row, row * 128 + (ks * 32 + lg * 8) * 2));
    }
#pragma unroll
    for (int cf = 0; cf < 2; ++cf) {
      const bf16x8 vf = *(const bf16x8*)(vb + (cf * 16 + lr) * 64 + ks * 32 + lg * 8);
#pragma unroll
      for (int rf = 0; rf < 4; ++rf)
        oacc[rf][cf] = __builtin_amdgcn_mfma_f32_16x16x32_bf16(pf[rf], vf, oacc[rf][cf], 0, 0, 0);
    }
  }
  bf16* ob = obuf + (size_t)win * 64 * 192 + head * 32;
#pragma unroll
  for (int rf = 0; rf < 4; ++rf)
#pragma unroll
    for (int cf = 0; cf < 2; ++cf)
#pragma unroll
      for (int jj = 0; jj < 4; ++jj) {
        const int tok = rf * 16 + lg * 4 + jj;
        const int d = cf * 16 + lr;
        ob[(size_t)tok * 192 + d] = (bf16)oacc[rf][cf][jj];
      }
}

// ---------------- K3: proj GEMM + window-reverse + residual -> x2 (fp32) ----------------
__global__ __launch_bounds__(256) void k3_proj(
    const bf16* __restrict__ obuf, const bf16* __restrict__ wproj,
    const float* __restrict__ projb, const float* __restrict__ x,
    float* __restrict__ x2) {
  __shared__ alignas(16) char a_lds[128 * 384];
  const int blk = blockIdx.x;
  const int tid = threadIdx.x;
  const bf16* src = obuf + (size_t)blk * 128 * 192;
#pragma unroll
  for (int it = 0; it < 12; ++it) {
    const int chunk = it * 256 + tid;
    const int row = chunk / 24, c8 = chunk % 24;
    *(uint4*)(a_lds + swz16(row, row * 384 + c8 * 16)) = *(const uint4*)(src + chunk * 8);
  }
  __syncthreads();
  const int wid = tid >> 6, lane = tid & 63, lr = lane & 15, lg = lane >> 4;
  const int wr = wid >> 1, wc = wid & 1;
  f32x4 acc[4][6] = {};
#pragma unroll
  for (int ks = 0; ks < 6; ++ks) {
    bf16x8 af[4];
#pragma unroll
    for (int rf = 0; rf < 4; ++rf) {
      const int row = wr * 64 + rf * 16 + lr;
      af[rf] = *(const bf16x8*)(a_lds + swz16(row, row * 384 + (ks * 32 + lg * 8) * 2));
    }
#pragma unroll
    for (int cf = 0; cf < 6; ++cf) {
      const int n = wc * 96 + cf * 16 + lr;
      const bf16x8 bfr = *(const bf16x8*)(wproj + n * 192 + ks * 32 + lg * 8);
#pragma unroll
      for (int rf = 0; rf < 4; ++rf)
        acc[rf][cf] = __builtin_amdgcn_mfma_f32_16x16x32_bf16(af[rf], bfr, acc[rf][cf], 0, 0, 0);
    }
  }
#pragma unroll
  for (int rf = 0; rf < 4; ++rf) {
#pragma unroll
    for (int jj = 0; jj < 4; ++jj) {
      const int grow = blk * 128 + wr * 64 + rf * 16 + lg * 4 + jj;
      const int win = grow >> 6, t = grow & 63;
      const int bb = win >> 8, wi = (win >> 4) & 15, wj = win & 15;
      const int oh = (wi * 8 + (t >> 3) + 4) & 127, ow = (wj * 8 + (t & 7) + 4) & 127;
      const size_t orow = (((size_t)bb * 128 + oh) * 128 + ow) * 192;
#pragma unroll
      for (int cf = 0; cf < 6; ++cf) {
        const int col = wc * 96 + cf * 16 + lr;
        x2[orow + col] = x[orow + col] + acc[rf][cf][jj] + projb[col];
      }
    }
  }
}

// ---------------- K4a: LN2 + MLP GEMM1 (K=192, N=768) + gelu -> h1 (bf16) ----------------
// 512 threads = 8 waves, 64 rows/block, each wave 96 cols. LDS = 24KB only.
__global__ __launch_bounds__(512) void k4a_mlp1(
    const float* __restrict__ x2, const float* __restrict__ n2w, const float* __restrict__ n2b,
    const bf16* __restrict__ w1t, const float* __restrict__ b1,
    bf16* __restrict__ h1) {
  __shared__ alignas(16) char a_lds[64 * 384];
  const int blk = blockIdx.x;
  const int tid = threadIdx.x;
  {
    const int t = tid >> 3, q = tid & 7;
    const float* xr = x2 + ((size_t)blk * 64 + t) * 192 + q * 24;
    float v[24];
    float s = 0.f, ss = 0.f;
#pragma unroll
    for (int u = 0; u < 6; ++u) {
      float4 f = ((const float4*)xr)[u];
      v[4 * u] = f.x; v[4 * u + 1] = f.y; v[4 * u + 2] = f.z; v[4 * u + 3] = f.w;
      s += (f.x + f.y) + (f.z + f.w);
      ss += (f.x * f.x + f.y * f.y) + (f.z * f.z + f.w * f.w);
    }
    s += __shfl_xor(s, 1); s += __shfl_xor(s, 2); s += __shfl_xor(s, 4);
    ss += __shfl_xor(ss, 1); ss += __shfl_xor(ss, 2); ss += __shfl_xor(ss, 4);
    const float mean = s * (1.f / 192.f);
    const float rstd = rsqrtf(ss * (1.f / 192.f) - mean * mean + EPS);
#pragma unroll
    for (int u = 0; u < 12; ++u) {
      const int c = q * 24 + 2 * u;
      const float g0 = (v[2 * u] - mean) * rstd * n2w[c] + n2b[c];
      const float g1 = (v[2 * u + 1] - mean) * rstd * n2w[c + 1] + n2b[c + 1];
      st_lds_bf16x2(a_lds, swz16(t, t * 384 + c * 2), g0, g1);
    }
  }
  __syncthreads();
  const int wid = tid >> 6, lane = tid & 63, lr = lane & 15, lg = lane >> 4;
  f32x4 acc[4][6] = {};
#pragma unroll
  for (int ks = 0; ks < 6; ++ks) {
    bf16x8 af[4];
#pragma unroll
    for (int rf = 0; rf < 4; ++rf) {
      const int row = rf * 16 + lr;
      af[rf] = *(const bf16x8*)(a_lds + swz16(row, row * 384 + (ks * 32 + lg * 8) * 2));
    }
#pragma unroll
    for (int cf = 0; cf < 6; ++cf) {
      const int n = wid * 96 + cf * 16 + lr;
      const bf16x8 bfr = *(const bf16x8*)(w1t + n * 192 + ks * 32 + lg * 8);
#pragma unroll
      for (int rf = 0; rf < 4; ++rf)
        acc[rf][cf] = __builtin_amdgcn_mfma_f32_16x16x32_bf16(af[rf], bfr, acc[rf][cf], 0, 0, 0);
    }
  }
#pragma unroll
  for (int cf = 0; cf < 6; ++cf) {
    const int col = wid * 96 + cf * 16 + lr;
    const float bb1 = b1[col];
#pragma unroll
    for (int rf = 0; rf < 4; ++rf)
#pragma unroll
      for (int jj = 0; jj < 4; ++jj) {
        const size_t hrow = (size_t)blk * 64 + rf * 16 + lg * 4 + jj;
        const float vv = acc[rf][cf][jj] + bb1;
        const float g = 0.5f * vv * (1.f + erff(vv * 0.70710678f));
        h1[hrow * 768 + col] = (bf16)g;
      }
  }
}

// ---------------- K4b: MLP GEMM2 (K=768, N=192) + residual -> out ----------------
// one wave per block, 32 rows, full 192 cols. No LDS.
__global__ __launch_bounds__(64) void k4b_mlp2(
    const bf16* __restrict__ h1, const bf16* __restrict__ w2t,
    const float* __restrict__ b2, const float* __restrict__ x2,
    float* __restrict__ out) {
  const int blk = blockIdx.x;
  const int lane = threadIdx.x, lr = lane & 15, lg = lane >> 4;
  const bf16* hb = h1 + (size_t)blk * 32 * 768;
  f32x4 acc[2][12] = {};
#pragma unroll 4
  for (int ks = 0; ks < 24; ++ks) {
    bf16x8 af[2];
#pragma unroll
    for (int rf = 0; rf < 2; ++rf)
      af[rf] = *(const bf16x8*)(hb + (size_t)(rf * 16 + lr) * 768 + ks * 32 + lg * 8);
#pragma unroll
    for (int cf = 0; cf < 12; ++cf) {
      const bf16x8 bfr = *(const bf16x8*)(w2t + (size_t)(cf * 16 + lr) * 768 + ks * 32 + lg * 8);
#pragma unroll
      for (int rf = 0; rf < 2; ++rf)
        acc[rf][cf] = __builtin_amdgcn_mfma_f32_16x16x32_bf16(af[rf], bfr, acc[rf][cf], 0, 0, 0);
    }
  }
#pragma unroll
  for (int rf = 0; rf < 2; ++rf) {
#pragma unroll
    for (int jj = 0; jj < 4; ++jj) {
      const size_t grow = (size_t)blk * 32 + rf * 16 + lg * 4 + jj;
#pragma unroll
      for (int cf = 0; cf < 12; ++cf) {
        const int col = cf * 16 + lr;
        out[grow * 192 + col] = x2[grow * 192 + col] + acc[rf][cf][jj] + b2[col];
      }
    }
  }
}

extern "C" void kernel_launch(void* const* d_in, const int* in_sizes, int n_in,
                              void* d_out, int out_size, void* d_ws, size_t ws_size,
                              hipStream_t stream) {
  (void)in_sizes; (void)n_in; (void)out_size; (void)ws_size;
  const float* x     = (const float*)d_in[0];
  const float* n1w   = (const float*)d_in[1];
  const float* n1b   = (const float*)d_in[2];
  const float* qkv_w = (const float*)d_in[3];
  const float* qkv_b = (const float*)d_in[4];
  const float* rel_b = (const float*)d_in[5];
  const float* proj_w= (const float*)d_in[6];
  const float* proj_b= (const float*)d_in[7];
  const float* n2w   = (const float*)d_in[8];
  const float* n2b   = (const float*)d_in[9];
  const float* w1    = (const float*)d_in[10];
  const float* b1    = (const float*)d_in[11];
  const float* w2    = (const float*)d_in[12];
  const float* b2    = (const float*)d_in[13];
  float* out = (float*)d_out;

  char* ws = (char*)d_ws;
  size_t off = 0;
  auto alloc = [&](size_t bytes) { char* p = ws + off; off += (bytes + 255) & ~(size_t)255; return p; };
  bf16* w_qkv_t  = (bf16*)alloc(576 * 192 * 2);
  bf16* w_proj_t = (bf16*)alloc(192 * 192 * 2);
  bf16* w_mlp1_t = (bf16*)alloc(768 * 192 * 2);
  bf16* w_mlp2_t = (bf16*)alloc(192 * 768 * 2);
  float* bias_tab = (float*)alloc(6 * 64 * 64 * 4);
  // q/k/vt/obuf region is EXACTLY 131072*768*2 bytes total (4 x 50,331,648,
  // each 256B-aligned already); h1 aliases it after k3 no longer needs them.
  bf16* qbuf  = (bf16*)alloc((size_t)2048 * 6 * 64 * 32 * 2);
  bf16* kbuf  = (bf16*)alloc((size_t)2048 * 6 * 64 * 32 * 2);
  bf16* vtbuf = (bf16*)alloc((size_t)2048 * 6 * 64 * 32 * 2);
  bf16* obuf  = (bf16*)alloc((size_t)131072 * 192 * 2);
  float* x2   = (float*)alloc((size_t)131072 * 192 * 4);
  bf16* h1 = qbuf;  // alias: dead after k3

  k_prep<<<1824, 256, 0, stream>>>(qkv_w, proj_w, w1, w2, rel_b,
                                   w_qkv_t, w_proj_t, w_mlp1_t, w_mlp2_t, bias_tab);
  k1_ln_qkv<<<2048, 256, 0, stream>>>(x, n1w, n1b, w_qkv_t, qkv_b, qbuf, kbuf, vtbuf);
  k2_attn<<<dim3(6, 2048), 64, 0, stream>>>(qbuf, kbuf, vtbuf, bias_tab, obuf);
  k3_proj<<<1024, 256, 0, stream>>>(obuf, w_proj_t, proj_b, x, x2);
  k4a_mlp1<<<2048, 512, 0, stream>>>(x2, n2w, n2b, w_mlp1_t, b1, h1);
  k4b_mlp2<<<4096, 64, 0, stream>>>(h1, w_mlp2_t, b2, x2, out);
}